// Round 5
// baseline (2042.477 us; speedup 1.0000x reference)
//
#include <hip/hip_runtime.h>
#include <hip/hip_bf16.h>

#define NB 32768
#define NSLOT 64
#define EPS 1e-5f

using bf16 = __hip_bfloat16;

// ---------- storage-type helpers (f32 or bf16 workspace) ----------
template<typename TY> __device__ __forceinline__ float ldF(const TY* p, size_t i);
template<> __device__ __forceinline__ float ldF<float>(const float* p, size_t i){ return p[i]; }
template<> __device__ __forceinline__ float ldF<bf16 >(const bf16*  p, size_t i){ return __bfloat162float(p[i]); }
template<typename TY> __device__ __forceinline__ void stF(TY* p, size_t i, float v);
template<> __device__ __forceinline__ void stF<float>(float* p, size_t i, float v){ p[i] = v; }
template<> __device__ __forceinline__ void stF<bf16 >(bf16*  p, size_t i, float v){ p[i] = __float2bfloat16(v); }

// y workspace layout (per tau, per sample): slot = k*64 + tg*16 + o, t = 4*k + tg.
// Lane l = tg*16+o stores slot k*64+l -> contiguous 256B wave stores (128B for k=4).

// weight-LDS word offsets (padded strides so 16 o-lanes hit 16 distinct banks):
#define OFF_W1 0       // t1w1 [16][73] (72 valid)    1168
#define OFF_W2 1168    // t2w1 [16][37] (36 valid)     592
#define OFF_W3 1760    // c1w1 [16][45]                720
#define OFF_C0 2480    // c0w  [12*9]                  108
#define OFF_B1 2588    // t1b1 16
#define OFF_B2 2604    // t2b1 16
#define OFF_B3 2620    // c1b1 16
#define OFF_C0B 2636   // c0b  9
#define WL_SIZE 2648

// ---------------- Kernel A: MLP + xcorr + first convs + BN1 stats ----------------
template<typename TY>
__global__ __launch_bounds__(256, 4)
void kA(const float* __restrict__ raw, const float* __restrict__ eegf,
        const float* __restrict__ fgw1, const float* __restrict__ fgb1,
        const float* __restrict__ fgw2, const float* __restrict__ fgb2,
        const float* __restrict__ t1w1, const float* __restrict__ t1b1,
        const float* __restrict__ t2w1, const float* __restrict__ t2b1,
        const float* __restrict__ c0w,  const float* __restrict__ c0b,
        const float* __restrict__ c1w1, const float* __restrict__ c1b1,
        TY* __restrict__ yws, float* __restrict__ stat1)
{
    __shared__ float raw_ec[4][756];   // raw; after xcorr reused as ec[t*9+d] (513 <= 756)
    __shared__ float eeg_s[4][684];    // [c][t] = c*57+t
    __shared__ float eegf_s[4][168];
    __shared__ float wl[WL_SIZE];
    __shared__ float h35_s[4][36];
    __shared__ float filt_s[4][8];
    __shared__ float stat_s[96];       // [tau*32 + o*2 + {sum,sq}]

    const int tid = threadIdx.x;
    const int l   = tid & 63;
    const int s   = tid >> 6;
    const int gs  = blockIdx.x * 4 + s;

    if (tid < 96) stat_s[tid] = 0.f;
    // stage weights (once per block)
    for (int idx = tid; idx < 1168; idx += 256) { int o = idx / 73, j = idx - o * 73; if (j < 72) wl[OFF_W1 + idx] = t1w1[o * 72 + j]; }
    for (int idx = tid; idx < 592;  idx += 256) { int o = idx / 37, j = idx - o * 37; if (j < 36) wl[OFF_W2 + idx] = t2w1[o * 36 + j]; }
    for (int idx = tid; idx < 720;  idx += 256) wl[OFF_W3 + idx] = c1w1[idx];
    for (int idx = tid; idx < 108;  idx += 256) wl[OFF_C0 + idx] = c0w[idx];
    if (tid < 16) { wl[OFF_B1 + tid] = t1b1[tid]; wl[OFF_B2 + tid] = t2b1[tid]; wl[OFF_B3 + tid] = c1b1[tid]; }
    if (tid < 9)  wl[OFF_C0B + tid] = c0b[tid];
    // stage raw + eegf (coalesced per wave)
    for (int r = l; r < 756; r += 64)
        raw_ec[s][r] = raw[(size_t)gs * 756 + r];
    for (int r = l; r < 168; r += 64)
        eegf_s[s][r] = eegf[(size_t)gs * 168 + r];
    __syncthreads();

    // h35 = tanh(eegf @ fg_w1 + b1)  (lanes 0..34, 4 accumulators; e from LDS broadcast)
    if (l < 35) {
        const float* e = &eegf_s[s][0];
        float a0 = 0.f, a1 = 0.f, a2 = 0.f, a3 = 0.f;
        for (int i = 0; i < 168; i += 4) {
            a0 = fmaf(e[i],     fgw1[i * 35 + l],       a0);
            a1 = fmaf(e[i + 1], fgw1[(i + 1) * 35 + l], a1);
            a2 = fmaf(e[i + 2], fgw1[(i + 2) * 35 + l], a2);
            a3 = fmaf(e[i + 3], fgw1[(i + 3) * 35 + l], a3);
        }
        h35_s[s][l] = tanhf(a0 + a1 + a2 + a3 + fgb1[l]);
    }
    __syncthreads();

    // filt = tanh(h35 @ fg_w2 + b2)  (lanes 0..6)
    if (l < 7) {
        float a = fgb2[l];
        for (int j = 0; j < 35; ++j) a = fmaf(h35_s[s][j], fgw2[j * 7 + l], a);
        filt_s[s][l] = tanhf(a);
    }
    __syncthreads();

    // xcorr: eeg[c][t] = sum_k raw[c*63+t+k]*filt[k]
    {
        float f0 = filt_s[s][0], f1 = filt_s[s][1], f2 = filt_s[s][2], f3 = filt_s[s][3],
              f4 = filt_s[s][4], f5 = filt_s[s][5], f6 = filt_s[s][6];
        for (int r = l; r < 684; r += 64) {
            int c = r / 57, t = r - c * 57;
            const float* rp = &raw_ec[s][c * 63 + t];
            float a = rp[0] * f0;
            a = fmaf(rp[1], f1, a); a = fmaf(rp[2], f2, a); a = fmaf(rp[3], f3, a);
            a = fmaf(rp[4], f4, a); a = fmaf(rp[5], f5, a); a = fmaf(rp[6], f6, a);
            eeg_s[s][r] = a;
        }
    }
    __syncthreads();

    const int o = l & 15, tg = l >> 4;      // t = 4*k + tg; k=4 valid only for tg<2
    const bool k4 = (tg < 2);

    // ---- tau=0: conv1d k=6 s=3 ----
    {
        const float b = wl[OFF_B1 + o];
        float a0 = b, a1 = b, a2 = b, a3 = b, a4 = b;
        const float* wbase = &wl[OFF_W1 + o * 73];
        for (int c = 0; c < 12; ++c) {
            const float* w = wbase + c * 6;
            float w0 = w[0], w1 = w[1], w2 = w[2], w3 = w[3], w4 = w[4], w5 = w[5];
            const float* ep = &eeg_s[s][c * 57 + 3 * tg];
            a0 = fmaf(ep[0],  w0, a0); a0 = fmaf(ep[1],  w1, a0); a0 = fmaf(ep[2],  w2, a0);
            a0 = fmaf(ep[3],  w3, a0); a0 = fmaf(ep[4],  w4, a0); a0 = fmaf(ep[5],  w5, a0);
            a1 = fmaf(ep[12], w0, a1); a1 = fmaf(ep[13], w1, a1); a1 = fmaf(ep[14], w2, a1);
            a1 = fmaf(ep[15], w3, a1); a1 = fmaf(ep[16], w4, a1); a1 = fmaf(ep[17], w5, a1);
            a2 = fmaf(ep[24], w0, a2); a2 = fmaf(ep[25], w1, a2); a2 = fmaf(ep[26], w2, a2);
            a2 = fmaf(ep[27], w3, a2); a2 = fmaf(ep[28], w4, a2); a2 = fmaf(ep[29], w5, a2);
            a3 = fmaf(ep[36], w0, a3); a3 = fmaf(ep[37], w1, a3); a3 = fmaf(ep[38], w2, a3);
            a3 = fmaf(ep[39], w3, a3); a3 = fmaf(ep[40], w4, a3); a3 = fmaf(ep[41], w5, a3);
            if (k4) {
                a4 = fmaf(ep[48], w0, a4); a4 = fmaf(ep[49], w1, a4); a4 = fmaf(ep[50], w2, a4);
                a4 = fmaf(ep[51], w3, a4); a4 = fmaf(ep[52], w4, a4); a4 = fmaf(ep[53], w5, a4);
            }
        }
        size_t base = (size_t)gs * 288 + l;
        stF<TY>(yws, base,       a0); stF<TY>(yws, base + 64,  a1);
        stF<TY>(yws, base + 128, a2); stF<TY>(yws, base + 192, a3);
        float sum = a0 + a1 + a2 + a3;
        float sq  = fmaf(a0, a0, fmaf(a1, a1, fmaf(a2, a2, a3 * a3)));
        if (k4) { stF<TY>(yws, base + 256, a4); sum += a4; sq = fmaf(a4, a4, sq); }
        sum += __shfl_xor(sum, 16); sq += __shfl_xor(sq, 16);
        sum += __shfl_xor(sum, 32); sq += __shfl_xor(sq, 32);
        if (tg == 0) { atomicAdd(&stat_s[o * 2], sum); atomicAdd(&stat_s[o * 2 + 1], sq); }
    }

    // ---- tau=1: conv1d k=3 d=2 s=3 ----
    {
        const float b = wl[OFF_B2 + o];
        float a0 = b, a1 = b, a2 = b, a3 = b, a4 = b;
        const float* wbase = &wl[OFF_W2 + o * 37];
        for (int c = 0; c < 12; ++c) {
            const float* w = wbase + c * 3;
            float w0 = w[0], w1 = w[1], w2 = w[2];
            const float* ep = &eeg_s[s][c * 57 + 3 * tg];
            a0 = fmaf(ep[0],  w0, a0); a0 = fmaf(ep[2],  w1, a0); a0 = fmaf(ep[4],  w2, a0);
            a1 = fmaf(ep[12], w0, a1); a1 = fmaf(ep[14], w1, a1); a1 = fmaf(ep[16], w2, a1);
            a2 = fmaf(ep[24], w0, a2); a2 = fmaf(ep[26], w1, a2); a2 = fmaf(ep[28], w2, a2);
            a3 = fmaf(ep[36], w0, a3); a3 = fmaf(ep[38], w1, a3); a3 = fmaf(ep[40], w2, a3);
            if (k4) {
                a4 = fmaf(ep[48], w0, a4); a4 = fmaf(ep[50], w1, a4); a4 = fmaf(ep[52], w2, a4);
            }
        }
        size_t base = (size_t)NB * 288 + (size_t)gs * 288 + l;
        stF<TY>(yws, base,       a0); stF<TY>(yws, base + 64,  a1);
        stF<TY>(yws, base + 128, a2); stF<TY>(yws, base + 192, a3);
        float sum = a0 + a1 + a2 + a3;
        float sq  = fmaf(a0, a0, fmaf(a1, a1, fmaf(a2, a2, a3 * a3)));
        if (k4) { stF<TY>(yws, base + 256, a4); sum += a4; sq = fmaf(a4, a4, sq); }
        sum += __shfl_xor(sum, 16); sq += __shfl_xor(sq, 16);
        sum += __shfl_xor(sum, 32); sq += __shfl_xor(sq, 32);
        if (tg == 0) { atomicAdd(&stat_s[32 + o * 2], sum); atomicAdd(&stat_s[32 + o * 2 + 1], sq); }
    }

    // ---- ec[t*9+d] = relu(channel-linear), overlaid on dead raw region ----
    float* ec = &raw_ec[s][0];
    for (int r = l; r < 513; r += 64) {
        int t = r / 9, d = r - t * 9;
        float a = wl[OFF_C0B + d];
        #pragma unroll
        for (int c = 0; c < 12; ++c) a = fmaf(eeg_s[s][c * 57 + t], wl[OFF_C0 + c * 9 + d], a);
        ec[r] = fmaxf(a, 0.f);
    }
    __syncthreads();

    // ---- tau=2: conv2d 5x9 stride (3,1) ----
    {
        const float b = wl[OFF_B3 + o];
        float a0 = b, a1 = b, a2 = b, a3 = b, a4 = b;
        const float* wbase = &wl[OFF_W3 + o * 45];
        #pragma unroll
        for (int kh = 0; kh < 5; ++kh) {
            const float* w = wbase + kh * 9;
            float w0 = w[0], w1 = w[1], w2 = w[2], w3 = w[3], w4 = w[4],
                  w5 = w[5], w6 = w[6], w7 = w[7], w8 = w[8];
            const float* ep = &ec[(3 * tg + kh) * 9];
            a0 = fmaf(ep[0], w0, a0); a0 = fmaf(ep[1], w1, a0); a0 = fmaf(ep[2], w2, a0);
            a0 = fmaf(ep[3], w3, a0); a0 = fmaf(ep[4], w4, a0); a0 = fmaf(ep[5], w5, a0);
            a0 = fmaf(ep[6], w6, a0); a0 = fmaf(ep[7], w7, a0); a0 = fmaf(ep[8], w8, a0);
            const float* e1 = ep + 108;
            a1 = fmaf(e1[0], w0, a1); a1 = fmaf(e1[1], w1, a1); a1 = fmaf(e1[2], w2, a1);
            a1 = fmaf(e1[3], w3, a1); a1 = fmaf(e1[4], w4, a1); a1 = fmaf(e1[5], w5, a1);
            a1 = fmaf(e1[6], w6, a1); a1 = fmaf(e1[7], w7, a1); a1 = fmaf(e1[8], w8, a1);
            const float* e2 = ep + 216;
            a2 = fmaf(e2[0], w0, a2); a2 = fmaf(e2[1], w1, a2); a2 = fmaf(e2[2], w2, a2);
            a2 = fmaf(e2[3], w3, a2); a2 = fmaf(e2[4], w4, a2); a2 = fmaf(e2[5], w5, a2);
            a2 = fmaf(e2[6], w6, a2); a2 = fmaf(e2[7], w7, a2); a2 = fmaf(e2[8], w8, a2);
            const float* e3 = ep + 324;
            a3 = fmaf(e3[0], w0, a3); a3 = fmaf(e3[1], w1, a3); a3 = fmaf(e3[2], w2, a3);
            a3 = fmaf(e3[3], w3, a3); a3 = fmaf(e3[4], w4, a3); a3 = fmaf(e3[5], w5, a3);
            a3 = fmaf(e3[6], w6, a3); a3 = fmaf(e3[7], w7, a3); a3 = fmaf(e3[8], w8, a3);
            if (k4) {
                const float* e4 = ep + 432;
                a4 = fmaf(e4[0], w0, a4); a4 = fmaf(e4[1], w1, a4); a4 = fmaf(e4[2], w2, a4);
                a4 = fmaf(e4[3], w3, a4); a4 = fmaf(e4[4], w4, a4); a4 = fmaf(e4[5], w5, a4);
                a4 = fmaf(e4[6], w6, a4); a4 = fmaf(e4[7], w7, a4); a4 = fmaf(e4[8], w8, a4);
            }
        }
        size_t base = (size_t)2 * NB * 288 + (size_t)gs * 288 + l;
        stF<TY>(yws, base,       a0); stF<TY>(yws, base + 64,  a1);
        stF<TY>(yws, base + 128, a2); stF<TY>(yws, base + 192, a3);
        float sum = a0 + a1 + a2 + a3;
        float sq  = fmaf(a0, a0, fmaf(a1, a1, fmaf(a2, a2, a3 * a3)));
        if (k4) { stF<TY>(yws, base + 256, a4); sum += a4; sq = fmaf(a4, a4, sq); }
        sum += __shfl_xor(sum, 16); sq += __shfl_xor(sq, 16);
        sum += __shfl_xor(sum, 32); sq += __shfl_xor(sq, 32);
        if (tg == 0) { atomicAdd(&stat_s[64 + o * 2], sum); atomicAdd(&stat_s[64 + o * 2 + 1], sq); }
    }
    __syncthreads();
    if (tid < 96) atomicAdd(&stat1[(blockIdx.x & (NSLOT - 1)) * 96 + tid], stat_s[tid]);
}

// ---------------- BN finalize (stage 1 or 2) ----------------
__global__ void kBN(const float* __restrict__ statp,
                    const float* __restrict__ g0, const float* __restrict__ be0,
                    const float* __restrict__ g1, const float* __restrict__ be1,
                    const float* __restrict__ g2, const float* __restrict__ be2,
                    float nInv, float* __restrict__ bnp)
{
    int tid = threadIdx.x;
    if (tid >= 48) return;
    int tau = tid / 16, o = tid % 16;
    float sum = 0.f, sq = 0.f;
    for (int sl = 0; sl < NSLOT; ++sl) {
        sum += statp[sl * 96 + tid * 2];
        sq  += statp[sl * 96 + tid * 2 + 1];
    }
    float mean = sum * nInv;
    float var  = sq * nInv - mean * mean;
    const float* g  = (tau == 0) ? g0 : (tau == 1) ? g1 : g2;
    const float* be = (tau == 0) ? be0 : (tau == 1) ? be1 : be2;
    float scale = g[o] / sqrtf(var + EPS);
    float shift = be[o] - mean * scale;
    bnp[tid * 2]     = scale;
    bnp[tid * 2 + 1] = shift;
}

// ---------------- Kernel C: BN1+relu, second convs, BN2 stats ----------------
template<typename TY>
__global__ __launch_bounds__(256)
void kC(const TY* __restrict__ yws, const float* __restrict__ bn1,
        const float* __restrict__ t1w2, const float* __restrict__ t1b2,
        const float* __restrict__ t2w2, const float* __restrict__ t2b2,
        const float* __restrict__ c1w2, const float* __restrict__ c1b2,
        TY* __restrict__ zws, float* __restrict__ stat2)
{
    __shared__ float h_s[3][4][288];
    __shared__ float z_s[3][4][80];
    __shared__ float bnp[96];
    const int tid = threadIdx.x;
    const int s0  = blockIdx.x * 4;

    if (tid < 96) bnp[tid] = bn1[tid];
    __syncthreads();

    // stage y: global reads are slot-contiguous (coalesced); invert slot->(o,t) for LDS
    for (int idx = tid; idx < 3456; idx += 256) {
        int tau = idx / 1152, rem = idx % 1152, s = rem / 288, slot = rem % 288;
        int k = slot >> 6, rr = slot & 63, tg = rr >> 4, o = rr & 15;
        int t = 4 * k + tg;
        float v = ldF<TY>(yws, (size_t)tau * NB * 288 + (size_t)(s0 + s) * 288 + slot);
        h_s[tau][s][o * 18 + t] = fmaxf(fmaf(v, bnp[(tau * 16 + o) * 2], bnp[(tau * 16 + o) * 2 + 1]), 0.f);
    }
    __syncthreads();

    for (int idx = tid; idx < 960; idx += 256) {
        int tau = idx / 320, rem = idx % 320, s = rem / 80, r = rem % 80;
        int o = r / 5, t = r % 5;
        float a;
        if (tau == 0) {
            a = t1b2[o];
            for (int c = 0; c < 16; ++c) {
                const float* hp = &h_s[0][s][c * 18 + 3 * t];
                const float* wp = &t1w2[o * 96 + c * 6];
                #pragma unroll
                for (int k = 0; k < 6; ++k) a = fmaf(hp[k], wp[k], a);
            }
        } else if (tau == 1) {
            a = t2b2[o];
            for (int c = 0; c < 16; ++c) {
                const float* hp = &h_s[1][s][c * 18 + 3 * t];
                const float* wp = &t2w2[o * 48 + c * 3];
                #pragma unroll
                for (int k = 0; k < 3; ++k) a = fmaf(hp[2 * k], wp[k], a);
            }
        } else {
            a = c1b2[o];
            for (int c = 0; c < 16; ++c) {
                const float* hp = &h_s[2][s][c * 18 + 3 * t];
                const float* wp = &c1w2[o * 80 + c * 5];
                #pragma unroll
                for (int k = 0; k < 5; ++k) a = fmaf(hp[k], wp[k], a);
            }
        }
        z_s[tau][s][r] = a;
    }
    __syncthreads();

    if (tid < 96) {
        int tau = tid / 32, rem = tid % 32, o = rem >> 1, st = rem & 1;
        float acc = 0.f;
        for (int s = 0; s < 4; ++s)
            for (int t = 0; t < 5; ++t) {
                float v = z_s[tau][s][o * 5 + t];
                acc += st ? v * v : v;
            }
        atomicAdd(&stat2[(blockIdx.x & (NSLOT - 1)) * 96 + tid], acc);
    }
    for (int idx = tid; idx < 960; idx += 256) {
        int tau = idx / 320, rem = idx % 320, s = rem / 80, r = rem % 80;
        stF<TY>(zws, (size_t)tau * NB * 80 + (size_t)(s0 + s) * 80 + r, z_s[tau][s][r]);
    }
}

// ---------------- Kernel E: BN2+relu, feats, FC, tanh ----------------
template<typename TY>
__global__ __launch_bounds__(256)
void kE(const TY* __restrict__ zws, const float* __restrict__ bn2,
        const float* __restrict__ fcw, const float* __restrict__ fcb,
        float* __restrict__ out)
{
    __shared__ float fcw_s[160 * 50];
    __shared__ float feats[8][320];
    __shared__ float fcb_s[50];
    __shared__ float bnp[96];
    const int tid = threadIdx.x;
    const int s0  = blockIdx.x * 8;

    for (int idx = tid; idx < 8000; idx += 256) fcw_s[idx] = fcw[idx];
    if (tid < 50) fcb_s[tid] = fcb[tid];
    if (tid >= 64 && tid < 160) bnp[tid - 64] = bn2[tid - 64];
    __syncthreads();

    for (int idx = tid; idx < 8 * 320; idx += 256) {
        int s = idx / 320, f = idx % 320;
        int g = f / 80; int tau = (g == 3) ? 2 : g;
        int r = f % 80, o = r / 5;
        float v = ldF<TY>(zws, (size_t)tau * NB * 80 + (size_t)(s0 + s) * 80 + r);
        feats[s][f] = fmaxf(fmaf(v, bnp[(tau * 16 + o) * 2], bnp[(tau * 16 + o) * 2 + 1]), 0.f);
    }
    __syncthreads();

    float accA = 0.f, accB = 0.f;
    int sA = tid / 50, uA = tid % 50;
    int iB = tid + 256, sB = iB / 50, uB = iB % 50;
    if (tid < 400) {
        accA = fcb_s[uA];
        for (int f = 0; f < 160; ++f) accA = fmaf(feats[sA][f], fcw_s[f * 50 + uA], accA);
    }
    if (tid < 144) {
        accB = fcb_s[uB];
        for (int f = 0; f < 160; ++f) accB = fmaf(feats[sB][f], fcw_s[f * 50 + uB], accB);
    }
    __syncthreads();
    for (int idx = tid; idx < 8000; idx += 256) fcw_s[idx] = fcw[8000 + idx];
    __syncthreads();
    if (tid < 400) {
        for (int f = 0; f < 160; ++f) accA = fmaf(feats[sA][160 + f], fcw_s[f * 50 + uA], accA);
        out[(size_t)(s0 + sA) * 50 + uA] = tanhf(accA);
    }
    if (tid < 144) {
        for (int f = 0; f < 160; ++f) accB = fmaf(feats[sB][160 + f], fcw_s[f * 50 + uB], accB);
        out[(size_t)(s0 + sB) * 50 + uB] = tanhf(accB);
    }
}

// ---------------- host launcher ----------------
template<typename TY>
static void launch_all(void* const* d_in, void* d_out, void* d_ws, hipStream_t stream)
{
    const float* raw  = (const float*)d_in[0];
    const float* eegf = (const float*)d_in[1];
    const float* fgw1 = (const float*)d_in[2];
    const float* fgb1 = (const float*)d_in[3];
    const float* fgw2 = (const float*)d_in[4];
    const float* fgb2 = (const float*)d_in[5];
    const float* t1w1 = (const float*)d_in[6];
    const float* t1b1 = (const float*)d_in[7];
    const float* t1g1 = (const float*)d_in[8];
    const float* t1be1= (const float*)d_in[9];
    const float* t1w2 = (const float*)d_in[10];
    const float* t1b2 = (const float*)d_in[11];
    const float* t1g2 = (const float*)d_in[12];
    const float* t1be2= (const float*)d_in[13];
    const float* t2w1 = (const float*)d_in[14];
    const float* t2b1 = (const float*)d_in[15];
    const float* t2g1 = (const float*)d_in[16];
    const float* t2be1= (const float*)d_in[17];
    const float* t2w2 = (const float*)d_in[18];
    const float* t2b2 = (const float*)d_in[19];
    const float* t2g2 = (const float*)d_in[20];
    const float* t2be2= (const float*)d_in[21];
    const float* c0w  = (const float*)d_in[22];
    const float* c0b  = (const float*)d_in[23];
    const float* c1w1 = (const float*)d_in[24];
    const float* c1b1 = (const float*)d_in[25];
    const float* c1g1 = (const float*)d_in[26];
    const float* c1be1= (const float*)d_in[27];
    const float* c1w2 = (const float*)d_in[28];
    const float* c1b2 = (const float*)d_in[29];
    const float* c1g2 = (const float*)d_in[30];
    const float* c1be2= (const float*)d_in[31];
    const float* fcw  = (const float*)d_in[32];
    const float* fcb  = (const float*)d_in[33];

    char* ws = (char*)d_ws;
    TY* yws = (TY*)ws;
    TY* zws = (TY*)(ws + (size_t)3 * NB * 288 * sizeof(TY));
    float* stat1 = (float*)(ws + (size_t)3 * NB * 288 * sizeof(TY) + (size_t)3 * NB * 80 * sizeof(TY));
    float* stat2 = stat1 + NSLOT * 96;
    float* bn1   = stat2 + NSLOT * 96;
    float* bn2   = bn1 + 96;

    hipMemsetAsync(stat1, 0, 2 * NSLOT * 96 * sizeof(float), stream);

    kA<TY><<<NB / 4, 256, 0, stream>>>(raw, eegf, fgw1, fgb1, fgw2, fgb2,
                                       t1w1, t1b1, t2w1, t2b1, c0w, c0b, c1w1, c1b1,
                                       yws, stat1);
    kBN<<<1, 64, 0, stream>>>(stat1, t1g1, t1be1, t2g1, t2be1, c1g1, c1be1,
                              1.f / (float)((size_t)NB * 18), bn1);
    kC<TY><<<NB / 4, 256, 0, stream>>>(yws, bn1, t1w2, t1b2, t2w2, t2b2, c1w2, c1b2,
                                       zws, stat2);
    kBN<<<1, 64, 0, stream>>>(stat2, t1g2, t1be2, t2g2, t2be2, c1g2, c1be2,
                              1.f / (float)((size_t)NB * 5), bn2);
    kE<TY><<<NB / 8, 256, 0, stream>>>(zws, bn2, fcw, fcb, (float*)d_out);
}

extern "C" void kernel_launch(void* const* d_in, const int* in_sizes, int n_in,
                              void* d_out, int out_size, void* d_ws, size_t ws_size,
                              hipStream_t stream)
{
    (void)in_sizes; (void)n_in; (void)out_size;
    size_t statBytes = (2 * NSLOT * 96 + 192) * sizeof(float);
    size_t needF32 = ((size_t)3 * NB * 288 + (size_t)3 * NB * 80) * 4 + statBytes;
    if (ws_size >= needF32)
        launch_all<float>(d_in, d_out, d_ws, stream);
    else
        launch_all<bf16>(d_in, d_out, d_ws, stream);
}

// Round 6
// 477.533 us; speedup vs baseline: 4.2771x; 4.2771x over previous
//
#include <hip/hip_runtime.h>
#include <hip/hip_bf16.h>

#define NB 32768
#define NSLOT 64
#define EPS 1e-5f

using bf16 = __hip_bfloat16;

// ---------- storage-type helpers (f32 or bf16 workspace) ----------
template<typename TY> __device__ __forceinline__ float ldF(const TY* p, size_t i);
template<> __device__ __forceinline__ float ldF<float>(const float* p, size_t i){ return p[i]; }
template<> __device__ __forceinline__ float ldF<bf16 >(const bf16*  p, size_t i){ return __bfloat162float(p[i]); }
template<typename TY> __device__ __forceinline__ void stF(TY* p, size_t i, float v);
template<> __device__ __forceinline__ void stF<float>(float* p, size_t i, float v){ p[i] = v; }
template<> __device__ __forceinline__ void stF<bf16 >(bf16*  p, size_t i, float v){ p[i] = __float2bfloat16(v); }

// y workspace layout (per tau, per sample): slot = k*64 + tg*16 + o, t = 4*k + tg.
// Lane l = tg*16+o stores slot k*64+l -> contiguous 256B wave stores (128B for k=4).

// weight-LDS word offsets (padded strides so 16 o-lanes hit 16 distinct banks):
#define OFF_W1 0       // t1w1 [16][73] (72 valid)    1168
#define OFF_W2 1168    // t2w1 [16][37] (36 valid)     592
#define OFF_W3 1760    // c1w1 [16][45]                720
#define OFF_C0 2480    // c0w  [12*9]                  108
#define OFF_B1 2588    // t1b1 16
#define OFF_B2 2604    // t2b1 16
#define OFF_B3 2620    // c1b1 16
#define OFF_C0B 2636   // c0b  9
#define WL_SIZE 2648

// ---------------- Kernel A: MLP + xcorr + first convs + BN1 stats ----------------
// NO min-waves clause: round 5 showed a forced VGPR cap => catastrophic scratch
// spill (3 GB writes). Uncapped this shape does not spill (round 4). Unroll
// pragmas bound load-pipelining so natural VGPR lands near/below 128.
template<typename TY>
__global__ __launch_bounds__(256)
void kA(const float* __restrict__ raw, const float* __restrict__ eegf,
        const float* __restrict__ fgw1, const float* __restrict__ fgb1,
        const float* __restrict__ fgw2, const float* __restrict__ fgb2,
        const float* __restrict__ t1w1, const float* __restrict__ t1b1,
        const float* __restrict__ t2w1, const float* __restrict__ t2b1,
        const float* __restrict__ c0w,  const float* __restrict__ c0b,
        const float* __restrict__ c1w1, const float* __restrict__ c1b1,
        TY* __restrict__ yws, float* __restrict__ stat1)
{
    __shared__ float raw_ec[4][756];   // raw; after xcorr reused as ec[t*9+d] (513 <= 756)
    __shared__ float eeg_s[4][684];    // [c][t] = c*57+t
    __shared__ float eegf_s[4][168];
    __shared__ float wl[WL_SIZE];
    __shared__ float h35_s[4][36];
    __shared__ float filt_s[4][8];
    __shared__ float stat_s[96];       // [tau*32 + o*2 + {sum,sq}]

    const int tid = threadIdx.x;
    const int l   = tid & 63;
    const int s   = tid >> 6;
    const int gs  = blockIdx.x * 4 + s;

    if (tid < 96) stat_s[tid] = 0.f;
    // stage weights (once per block)
    for (int idx = tid; idx < 1168; idx += 256) { int o = idx / 73, j = idx - o * 73; if (j < 72) wl[OFF_W1 + idx] = t1w1[o * 72 + j]; }
    for (int idx = tid; idx < 592;  idx += 256) { int o = idx / 37, j = idx - o * 37; if (j < 36) wl[OFF_W2 + idx] = t2w1[o * 36 + j]; }
    for (int idx = tid; idx < 720;  idx += 256) wl[OFF_W3 + idx] = c1w1[idx];
    for (int idx = tid; idx < 108;  idx += 256) wl[OFF_C0 + idx] = c0w[idx];
    if (tid < 16) { wl[OFF_B1 + tid] = t1b1[tid]; wl[OFF_B2 + tid] = t2b1[tid]; wl[OFF_B3 + tid] = c1b1[tid]; }
    if (tid < 9)  wl[OFF_C0B + tid] = c0b[tid];
    // stage raw + eegf (coalesced per wave)
    for (int r = l; r < 756; r += 64)
        raw_ec[s][r] = raw[(size_t)gs * 756 + r];
    for (int r = l; r < 168; r += 64)
        eegf_s[s][r] = eegf[(size_t)gs * 168 + r];
    __syncthreads();

    // h35 = tanh(eegf @ fg_w1 + b1)  (lanes 0..34, 4 accumulators; e from LDS broadcast)
    if (l < 35) {
        const float* e = &eegf_s[s][0];
        float a0 = 0.f, a1 = 0.f, a2 = 0.f, a3 = 0.f;
        #pragma unroll 2
        for (int i = 0; i < 168; i += 4) {
            a0 = fmaf(e[i],     fgw1[i * 35 + l],       a0);
            a1 = fmaf(e[i + 1], fgw1[(i + 1) * 35 + l], a1);
            a2 = fmaf(e[i + 2], fgw1[(i + 2) * 35 + l], a2);
            a3 = fmaf(e[i + 3], fgw1[(i + 3) * 35 + l], a3);
        }
        h35_s[s][l] = tanhf(a0 + a1 + a2 + a3 + fgb1[l]);
    }
    __syncthreads();

    // filt = tanh(h35 @ fg_w2 + b2)  (lanes 0..6)
    if (l < 7) {
        float a = fgb2[l];
        for (int j = 0; j < 35; ++j) a = fmaf(h35_s[s][j], fgw2[j * 7 + l], a);
        filt_s[s][l] = tanhf(a);
    }
    __syncthreads();

    // xcorr: eeg[c][t] = sum_k raw[c*63+t+k]*filt[k]
    {
        float f0 = filt_s[s][0], f1 = filt_s[s][1], f2 = filt_s[s][2], f3 = filt_s[s][3],
              f4 = filt_s[s][4], f5 = filt_s[s][5], f6 = filt_s[s][6];
        for (int r = l; r < 684; r += 64) {
            int c = r / 57, t = r - c * 57;
            const float* rp = &raw_ec[s][c * 63 + t];
            float a = rp[0] * f0;
            a = fmaf(rp[1], f1, a); a = fmaf(rp[2], f2, a); a = fmaf(rp[3], f3, a);
            a = fmaf(rp[4], f4, a); a = fmaf(rp[5], f5, a); a = fmaf(rp[6], f6, a);
            eeg_s[s][r] = a;
        }
    }
    __syncthreads();

    const int o = l & 15, tg = l >> 4;      // t = 4*k + tg; k=4 valid only for tg<2
    const bool k4 = (tg < 2);

    // ---- tau=0: conv1d k=6 s=3 ----
    {
        const float b = wl[OFF_B1 + o];
        float a0 = b, a1 = b, a2 = b, a3 = b, a4 = b;
        const float* wbase = &wl[OFF_W1 + o * 73];
        #pragma unroll 3
        for (int c = 0; c < 12; ++c) {
            const float* w = wbase + c * 6;
            float w0 = w[0], w1 = w[1], w2 = w[2], w3 = w[3], w4 = w[4], w5 = w[5];
            const float* ep = &eeg_s[s][c * 57 + 3 * tg];
            a0 = fmaf(ep[0],  w0, a0); a0 = fmaf(ep[1],  w1, a0); a0 = fmaf(ep[2],  w2, a0);
            a0 = fmaf(ep[3],  w3, a0); a0 = fmaf(ep[4],  w4, a0); a0 = fmaf(ep[5],  w5, a0);
            a1 = fmaf(ep[12], w0, a1); a1 = fmaf(ep[13], w1, a1); a1 = fmaf(ep[14], w2, a1);
            a1 = fmaf(ep[15], w3, a1); a1 = fmaf(ep[16], w4, a1); a1 = fmaf(ep[17], w5, a1);
            a2 = fmaf(ep[24], w0, a2); a2 = fmaf(ep[25], w1, a2); a2 = fmaf(ep[26], w2, a2);
            a2 = fmaf(ep[27], w3, a2); a2 = fmaf(ep[28], w4, a2); a2 = fmaf(ep[29], w5, a2);
            a3 = fmaf(ep[36], w0, a3); a3 = fmaf(ep[37], w1, a3); a3 = fmaf(ep[38], w2, a3);
            a3 = fmaf(ep[39], w3, a3); a3 = fmaf(ep[40], w4, a3); a3 = fmaf(ep[41], w5, a3);
            if (k4) {
                a4 = fmaf(ep[48], w0, a4); a4 = fmaf(ep[49], w1, a4); a4 = fmaf(ep[50], w2, a4);
                a4 = fmaf(ep[51], w3, a4); a4 = fmaf(ep[52], w4, a4); a4 = fmaf(ep[53], w5, a4);
            }
        }
        size_t base = (size_t)gs * 288 + l;
        stF<TY>(yws, base,       a0); stF<TY>(yws, base + 64,  a1);
        stF<TY>(yws, base + 128, a2); stF<TY>(yws, base + 192, a3);
        float sum = a0 + a1 + a2 + a3;
        float sq  = fmaf(a0, a0, fmaf(a1, a1, fmaf(a2, a2, a3 * a3)));
        if (k4) { stF<TY>(yws, base + 256, a4); sum += a4; sq = fmaf(a4, a4, sq); }
        sum += __shfl_xor(sum, 16); sq += __shfl_xor(sq, 16);
        sum += __shfl_xor(sum, 32); sq += __shfl_xor(sq, 32);
        if (tg == 0) { atomicAdd(&stat_s[o * 2], sum); atomicAdd(&stat_s[o * 2 + 1], sq); }
    }

    // ---- tau=1: conv1d k=3 d=2 s=3 ----
    {
        const float b = wl[OFF_B2 + o];
        float a0 = b, a1 = b, a2 = b, a3 = b, a4 = b;
        const float* wbase = &wl[OFF_W2 + o * 37];
        #pragma unroll 3
        for (int c = 0; c < 12; ++c) {
            const float* w = wbase + c * 3;
            float w0 = w[0], w1 = w[1], w2 = w[2];
            const float* ep = &eeg_s[s][c * 57 + 3 * tg];
            a0 = fmaf(ep[0],  w0, a0); a0 = fmaf(ep[2],  w1, a0); a0 = fmaf(ep[4],  w2, a0);
            a1 = fmaf(ep[12], w0, a1); a1 = fmaf(ep[14], w1, a1); a1 = fmaf(ep[16], w2, a1);
            a2 = fmaf(ep[24], w0, a2); a2 = fmaf(ep[26], w1, a2); a2 = fmaf(ep[28], w2, a2);
            a3 = fmaf(ep[36], w0, a3); a3 = fmaf(ep[38], w1, a3); a3 = fmaf(ep[40], w2, a3);
            if (k4) {
                a4 = fmaf(ep[48], w0, a4); a4 = fmaf(ep[50], w1, a4); a4 = fmaf(ep[52], w2, a4);
            }
        }
        size_t base = (size_t)NB * 288 + (size_t)gs * 288 + l;
        stF<TY>(yws, base,       a0); stF<TY>(yws, base + 64,  a1);
        stF<TY>(yws, base + 128, a2); stF<TY>(yws, base + 192, a3);
        float sum = a0 + a1 + a2 + a3;
        float sq  = fmaf(a0, a0, fmaf(a1, a1, fmaf(a2, a2, a3 * a3)));
        if (k4) { stF<TY>(yws, base + 256, a4); sum += a4; sq = fmaf(a4, a4, sq); }
        sum += __shfl_xor(sum, 16); sq += __shfl_xor(sq, 16);
        sum += __shfl_xor(sum, 32); sq += __shfl_xor(sq, 32);
        if (tg == 0) { atomicAdd(&stat_s[32 + o * 2], sum); atomicAdd(&stat_s[32 + o * 2 + 1], sq); }
    }

    // ---- ec[t*9+d] = relu(channel-linear), overlaid on dead raw region ----
    float* ec = &raw_ec[s][0];
    for (int r = l; r < 513; r += 64) {
        int t = r / 9, d = r - t * 9;
        float a = wl[OFF_C0B + d];
        #pragma unroll
        for (int c = 0; c < 12; ++c) a = fmaf(eeg_s[s][c * 57 + t], wl[OFF_C0 + c * 9 + d], a);
        ec[r] = fmaxf(a, 0.f);
    }
    __syncthreads();

    // ---- tau=2: conv2d 5x9 stride (3,1) ----
    {
        const float b = wl[OFF_B3 + o];
        float a0 = b, a1 = b, a2 = b, a3 = b, a4 = b;
        const float* wbase = &wl[OFF_W3 + o * 45];
        #pragma unroll 2
        for (int kh = 0; kh < 5; ++kh) {
            const float* w = wbase + kh * 9;
            float w0 = w[0], w1 = w[1], w2 = w[2], w3 = w[3], w4 = w[4],
                  w5 = w[5], w6 = w[6], w7 = w[7], w8 = w[8];
            const float* ep = &ec[(3 * tg + kh) * 9];
            a0 = fmaf(ep[0], w0, a0); a0 = fmaf(ep[1], w1, a0); a0 = fmaf(ep[2], w2, a0);
            a0 = fmaf(ep[3], w3, a0); a0 = fmaf(ep[4], w4, a0); a0 = fmaf(ep[5], w5, a0);
            a0 = fmaf(ep[6], w6, a0); a0 = fmaf(ep[7], w7, a0); a0 = fmaf(ep[8], w8, a0);
            const float* e1 = ep + 108;
            a1 = fmaf(e1[0], w0, a1); a1 = fmaf(e1[1], w1, a1); a1 = fmaf(e1[2], w2, a1);
            a1 = fmaf(e1[3], w3, a1); a1 = fmaf(e1[4], w4, a1); a1 = fmaf(e1[5], w5, a1);
            a1 = fmaf(e1[6], w6, a1); a1 = fmaf(e1[7], w7, a1); a1 = fmaf(e1[8], w8, a1);
            const float* e2 = ep + 216;
            a2 = fmaf(e2[0], w0, a2); a2 = fmaf(e2[1], w1, a2); a2 = fmaf(e2[2], w2, a2);
            a2 = fmaf(e2[3], w3, a2); a2 = fmaf(e2[4], w4, a2); a2 = fmaf(e2[5], w5, a2);
            a2 = fmaf(e2[6], w6, a2); a2 = fmaf(e2[7], w7, a2); a2 = fmaf(e2[8], w8, a2);
            const float* e3 = ep + 324;
            a3 = fmaf(e3[0], w0, a3); a3 = fmaf(e3[1], w1, a3); a3 = fmaf(e3[2], w2, a3);
            a3 = fmaf(e3[3], w3, a3); a3 = fmaf(e3[4], w4, a3); a3 = fmaf(e3[5], w5, a3);
            a3 = fmaf(e3[6], w6, a3); a3 = fmaf(e3[7], w7, a3); a3 = fmaf(e3[8], w8, a3);
            if (k4) {
                const float* e4 = ep + 432;
                a4 = fmaf(e4[0], w0, a4); a4 = fmaf(e4[1], w1, a4); a4 = fmaf(e4[2], w2, a4);
                a4 = fmaf(e4[3], w3, a4); a4 = fmaf(e4[4], w4, a4); a4 = fmaf(e4[5], w5, a4);
                a4 = fmaf(e4[6], w6, a4); a4 = fmaf(e4[7], w7, a4); a4 = fmaf(e4[8], w8, a4);
            }
        }
        size_t base = (size_t)2 * NB * 288 + (size_t)gs * 288 + l;
        stF<TY>(yws, base,       a0); stF<TY>(yws, base + 64,  a1);
        stF<TY>(yws, base + 128, a2); stF<TY>(yws, base + 192, a3);
        float sum = a0 + a1 + a2 + a3;
        float sq  = fmaf(a0, a0, fmaf(a1, a1, fmaf(a2, a2, a3 * a3)));
        if (k4) { stF<TY>(yws, base + 256, a4); sum += a4; sq = fmaf(a4, a4, sq); }
        sum += __shfl_xor(sum, 16); sq += __shfl_xor(sq, 16);
        sum += __shfl_xor(sum, 32); sq += __shfl_xor(sq, 32);
        if (tg == 0) { atomicAdd(&stat_s[64 + o * 2], sum); atomicAdd(&stat_s[64 + o * 2 + 1], sq); }
    }
    __syncthreads();
    if (tid < 96) atomicAdd(&stat1[(blockIdx.x & (NSLOT - 1)) * 96 + tid], stat_s[tid]);
}

// ---------------- BN finalize (stage 1 or 2) ----------------
__global__ void kBN(const float* __restrict__ statp,
                    const float* __restrict__ g0, const float* __restrict__ be0,
                    const float* __restrict__ g1, const float* __restrict__ be1,
                    const float* __restrict__ g2, const float* __restrict__ be2,
                    float nInv, float* __restrict__ bnp)
{
    int tid = threadIdx.x;
    if (tid >= 48) return;
    int tau = tid / 16, o = tid % 16;
    float sum = 0.f, sq = 0.f;
    for (int sl = 0; sl < NSLOT; ++sl) {
        sum += statp[sl * 96 + tid * 2];
        sq  += statp[sl * 96 + tid * 2 + 1];
    }
    float mean = sum * nInv;
    float var  = sq * nInv - mean * mean;
    const float* g  = (tau == 0) ? g0 : (tau == 1) ? g1 : g2;
    const float* be = (tau == 0) ? be0 : (tau == 1) ? be1 : be2;
    float scale = g[o] / sqrtf(var + EPS);
    float shift = be[o] - mean * scale;
    bnp[tid * 2]     = scale;
    bnp[tid * 2 + 1] = shift;
}

// ---------------- Kernel C: BN1+relu, second convs, BN2 stats ----------------
template<typename TY>
__global__ __launch_bounds__(256)
void kC(const TY* __restrict__ yws, const float* __restrict__ bn1,
        const float* __restrict__ t1w2, const float* __restrict__ t1b2,
        const float* __restrict__ t2w2, const float* __restrict__ t2b2,
        const float* __restrict__ c1w2, const float* __restrict__ c1b2,
        TY* __restrict__ zws, float* __restrict__ stat2)
{
    __shared__ float h_s[3][4][288];
    __shared__ float z_s[3][4][80];
    __shared__ float bnp[96];
    const int tid = threadIdx.x;
    const int s0  = blockIdx.x * 4;

    if (tid < 96) bnp[tid] = bn1[tid];
    __syncthreads();

    // stage y: global reads are slot-contiguous (coalesced); invert slot->(o,t) for LDS
    for (int idx = tid; idx < 3456; idx += 256) {
        int tau = idx / 1152, rem = idx % 1152, s = rem / 288, slot = rem % 288;
        int k = slot >> 6, rr = slot & 63, tg = rr >> 4, o = rr & 15;
        int t = 4 * k + tg;
        float v = ldF<TY>(yws, (size_t)tau * NB * 288 + (size_t)(s0 + s) * 288 + slot);
        h_s[tau][s][o * 18 + t] = fmaxf(fmaf(v, bnp[(tau * 16 + o) * 2], bnp[(tau * 16 + o) * 2 + 1]), 0.f);
    }
    __syncthreads();

    for (int idx = tid; idx < 960; idx += 256) {
        int tau = idx / 320, rem = idx % 320, s = rem / 80, r = rem % 80;
        int o = r / 5, t = r % 5;
        float a;
        if (tau == 0) {
            a = t1b2[o];
            for (int c = 0; c < 16; ++c) {
                const float* hp = &h_s[0][s][c * 18 + 3 * t];
                const float* wp = &t1w2[o * 96 + c * 6];
                #pragma unroll
                for (int k = 0; k < 6; ++k) a = fmaf(hp[k], wp[k], a);
            }
        } else if (tau == 1) {
            a = t2b2[o];
            for (int c = 0; c < 16; ++c) {
                const float* hp = &h_s[1][s][c * 18 + 3 * t];
                const float* wp = &t2w2[o * 48 + c * 3];
                #pragma unroll
                for (int k = 0; k < 3; ++k) a = fmaf(hp[2 * k], wp[k], a);
            }
        } else {
            a = c1b2[o];
            for (int c = 0; c < 16; ++c) {
                const float* hp = &h_s[2][s][c * 18 + 3 * t];
                const float* wp = &c1w2[o * 80 + c * 5];
                #pragma unroll
                for (int k = 0; k < 5; ++k) a = fmaf(hp[k], wp[k], a);
            }
        }
        z_s[tau][s][r] = a;
    }
    __syncthreads();

    if (tid < 96) {
        int tau = tid / 32, rem = tid % 32, o = rem >> 1, st = rem & 1;
        float acc = 0.f;
        for (int s = 0; s < 4; ++s)
            for (int t = 0; t < 5; ++t) {
                float v = z_s[tau][s][o * 5 + t];
                acc += st ? v * v : v;
            }
        atomicAdd(&stat2[(blockIdx.x & (NSLOT - 1)) * 96 + tid], acc);
    }
    for (int idx = tid; idx < 960; idx += 256) {
        int tau = idx / 320, rem = idx % 320, s = rem / 80, r = rem % 80;
        stF<TY>(zws, (size_t)tau * NB * 80 + (size_t)(s0 + s) * 80 + r, z_s[tau][s][r]);
    }
}

// ---------------- Kernel E: BN2+relu, feats, FC, tanh ----------------
template<typename TY>
__global__ __launch_bounds__(256)
void kE(const TY* __restrict__ zws, const float* __restrict__ bn2,
        const float* __restrict__ fcw, const float* __restrict__ fcb,
        float* __restrict__ out)
{
    __shared__ float fcw_s[160 * 50];
    __shared__ float feats[8][320];
    __shared__ float fcb_s[50];
    __shared__ float bnp[96];
    const int tid = threadIdx.x;
    const int s0  = blockIdx.x * 8;

    for (int idx = tid; idx < 8000; idx += 256) fcw_s[idx] = fcw[idx];
    if (tid < 50) fcb_s[tid] = fcb[tid];
    if (tid >= 64 && tid < 160) bnp[tid - 64] = bn2[tid - 64];
    __syncthreads();

    for (int idx = tid; idx < 8 * 320; idx += 256) {
        int s = idx / 320, f = idx % 320;
        int g = f / 80; int tau = (g == 3) ? 2 : g;
        int r = f % 80, o = r / 5;
        float v = ldF<TY>(zws, (size_t)tau * NB * 80 + (size_t)(s0 + s) * 80 + r);
        feats[s][f] = fmaxf(fmaf(v, bnp[(tau * 16 + o) * 2], bnp[(tau * 16 + o) * 2 + 1]), 0.f);
    }
    __syncthreads();

    float accA = 0.f, accB = 0.f;
    int sA = tid / 50, uA = tid % 50;
    int iB = tid + 256, sB = iB / 50, uB = iB % 50;
    if (tid < 400) {
        accA = fcb_s[uA];
        for (int f = 0; f < 160; ++f) accA = fmaf(feats[sA][f], fcw_s[f * 50 + uA], accA);
    }
    if (tid < 144) {
        accB = fcb_s[uB];
        for (int f = 0; f < 160; ++f) accB = fmaf(feats[sB][f], fcw_s[f * 50 + uB], accB);
    }
    __syncthreads();
    for (int idx = tid; idx < 8000; idx += 256) fcw_s[idx] = fcw[8000 + idx];
    __syncthreads();
    if (tid < 400) {
        for (int f = 0; f < 160; ++f) accA = fmaf(feats[sA][160 + f], fcw_s[f * 50 + uA], accA);
        out[(size_t)(s0 + sA) * 50 + uA] = tanhf(accA);
    }
    if (tid < 144) {
        for (int f = 0; f < 160; ++f) accB = fmaf(feats[sB][160 + f], fcw_s[f * 50 + uB], accB);
        out[(size_t)(s0 + sB) * 50 + uB] = tanhf(accB);
    }
}

// ---------------- host launcher ----------------
template<typename TY>
static void launch_all(void* const* d_in, void* d_out, void* d_ws, hipStream_t stream)
{
    const float* raw  = (const float*)d_in[0];
    const float* eegf = (const float*)d_in[1];
    const float* fgw1 = (const float*)d_in[2];
    const float* fgb1 = (const float*)d_in[3];
    const float* fgw2 = (const float*)d_in[4];
    const float* fgb2 = (const float*)d_in[5];
    const float* t1w1 = (const float*)d_in[6];
    const float* t1b1 = (const float*)d_in[7];
    const float* t1g1 = (const float*)d_in[8];
    const float* t1be1= (const float*)d_in[9];
    const float* t1w2 = (const float*)d_in[10];
    const float* t1b2 = (const float*)d_in[11];
    const float* t1g2 = (const float*)d_in[12];
    const float* t1be2= (const float*)d_in[13];
    const float* t2w1 = (const float*)d_in[14];
    const float* t2b1 = (const float*)d_in[15];
    const float* t2g1 = (const float*)d_in[16];
    const float* t2be1= (const float*)d_in[17];
    const float* t2w2 = (const float*)d_in[18];
    const float* t2b2 = (const float*)d_in[19];
    const float* t2g2 = (const float*)d_in[20];
    const float* t2be2= (const float*)d_in[21];
    const float* c0w  = (const float*)d_in[22];
    const float* c0b  = (const float*)d_in[23];
    const float* c1w1 = (const float*)d_in[24];
    const float* c1b1 = (const float*)d_in[25];
    const float* c1g1 = (const float*)d_in[26];
    const float* c1be1= (const float*)d_in[27];
    const float* c1w2 = (const float*)d_in[28];
    const float* c1b2 = (const float*)d_in[29];
    const float* c1g2 = (const float*)d_in[30];
    const float* c1be2= (const float*)d_in[31];
    const float* fcw  = (const float*)d_in[32];
    const float* fcb  = (const float*)d_in[33];

    char* ws = (char*)d_ws;
    TY* yws = (TY*)ws;
    TY* zws = (TY*)(ws + (size_t)3 * NB * 288 * sizeof(TY));
    float* stat1 = (float*)(ws + (size_t)3 * NB * 288 * sizeof(TY) + (size_t)3 * NB * 80 * sizeof(TY));
    float* stat2 = stat1 + NSLOT * 96;
    float* bn1   = stat2 + NSLOT * 96;
    float* bn2   = bn1 + 96;

    hipMemsetAsync(stat1, 0, 2 * NSLOT * 96 * sizeof(float), stream);

    kA<TY><<<NB / 4, 256, 0, stream>>>(raw, eegf, fgw1, fgb1, fgw2, fgb2,
                                       t1w1, t1b1, t2w1, t2b1, c0w, c0b, c1w1, c1b1,
                                       yws, stat1);
    kBN<<<1, 64, 0, stream>>>(stat1, t1g1, t1be1, t2g1, t2be1, c1g1, c1be1,
                              1.f / (float)((size_t)NB * 18), bn1);
    kC<TY><<<NB / 4, 256, 0, stream>>>(yws, bn1, t1w2, t1b2, t2w2, t2b2, c1w2, c1b2,
                                       zws, stat2);
    kBN<<<1, 64, 0, stream>>>(stat2, t1g2, t1be2, t2g2, t2be2, c1g2, c1be2,
                              1.f / (float)((size_t)NB * 5), bn2);
    kE<TY><<<NB / 8, 256, 0, stream>>>(zws, bn2, fcw, fcb, (float*)d_out);
}

extern "C" void kernel_launch(void* const* d_in, const int* in_sizes, int n_in,
                              void* d_out, int out_size, void* d_ws, size_t ws_size,
                              hipStream_t stream)
{
    (void)in_sizes; (void)n_in; (void)out_size;
    size_t statBytes = (2 * NSLOT * 96 + 192) * sizeof(float);
    size_t needF32 = ((size_t)3 * NB * 288 + (size_t)3 * NB * 80) * 4 + statBytes;
    if (ws_size >= needF32)
        launch_all<float>(d_in, d_out, d_ws, stream);
    else
        launch_all<bf16>(d_in, d_out, d_ws, stream);
}